// Round 1
// baseline (1873.244 us; speedup 1.0000x reference)
//
#include <hip/hip_runtime.h>
#include <cstdint>
#include <cstddef>

#define NNODES 50000
#define TT 24
#define DYNF 16
#define STATF 8
#define HDIM 64
#define NEDGES 1600000

__device__ __forceinline__ float fast_sigmoid(float x) {
    float e = __expf(-x);
    return __builtin_amdgcn_rcpf(1.f + e);
}
// robust fast tanh: no inf/inf NaN at extremes
__device__ __forceinline__ float fast_tanh(float x) {
    float e = __expf(2.f * x);
    return 1.f - 2.f * __builtin_amdgcn_rcpf(e + 1.f);
}

// ---------------------------------------------------------------------------
// GRU over T=24 steps, fused with the W1 transform of GCN layer 1.
// Block = 256 threads = 64 nodes x 4 feature-slices (16 hidden feats each).
// h shared across the 4 slices via double-buffered LDS (1 barrier/step).
// Weight indices are wave-uniform -> s_load (SGPR operands, no VGPR cost).
// ---------------------------------------------------------------------------
__global__ __launch_bounds__(256) void gru_w1_kernel(
    const float* __restrict__ x_dyn, const float* __restrict__ x_stat,
    const float* __restrict__ Wih, const float* __restrict__ Whh,
    const float* __restrict__ bih, const float* __restrict__ bhh,
    const float* __restrict__ W1, float* __restrict__ t1)
{
    constexpr int S = 65;               // LDS row stride (pad: 2-way max -> free)
    __shared__ float hl[2][64 * S];
    const int nl = threadIdx.x & 63;    // node within block (lane)
    const int p = __builtin_amdgcn_readfirstlane((int)(threadIdx.x >> 6)); // slice 0..3
    const int node = blockIdx.x * 64 + nl;
    const bool valid = node < NNODES;
    const int nclamp = valid ? node : 0;

    for (int i = threadIdx.x; i < 64 * S; i += 256) hl[0][i] = 0.f;
    __syncthreads();

    const float* xrow = x_dyn + (size_t)nclamp * (TT * DYNF);

    for (int t = 0; t < TT; ++t) {
        const float* rb = hl[t & 1];
        float* wb = hl[(t + 1) & 1];

        float x[DYNF];
        if (valid) {
            const float4* x4 = reinterpret_cast<const float4*>(xrow + t * DYNF);
            #pragma unroll
            for (int c = 0; c < 4; ++c) {
                float4 v = x4[c];
                x[c*4+0] = v.x; x[c*4+1] = v.y; x[c*4+2] = v.z; x[c*4+3] = v.w;
            }
        } else {
            #pragma unroll
            for (int i = 0; i < DYNF; ++i) x[i] = 0.f;
        }

        float h[HDIM];
        #pragma unroll
        for (int k = 0; k < HDIM; ++k) h[k] = rb[nl * S + k];

        for (int jj = 0; jj < 16; ++jj) {      // rolled: keeps I$ small
            const int j = p * 16 + jj;         // wave-uniform -> s_load weights
            float ar  = bih[j]          + bhh[j];
            float az  = bih[HDIM + j]   + bhh[HDIM + j];
            float anx = bih[2*HDIM + j];
            float anh = bhh[2*HDIM + j];
            #pragma unroll
            for (int k = 0; k < DYNF; ++k) {
                float xv = x[k];
                ar  += Wih[j*DYNF + k]          * xv;
                az  += Wih[(HDIM+j)*DYNF + k]   * xv;
                anx += Wih[(2*HDIM+j)*DYNF + k] * xv;
            }
            #pragma unroll
            for (int k = 0; k < HDIM; ++k) {
                float hv = h[k];
                ar  += Whh[j*HDIM + k]          * hv;
                az  += Whh[(HDIM+j)*HDIM + k]   * hv;
                anh += Whh[(2*HDIM+j)*HDIM + k] * hv;
            }
            float r = fast_sigmoid(ar);
            float z = fast_sigmoid(az);
            float n = fast_tanh(anx + r * anh);
            wb[nl * S + j] = (1.f - z) * n + z * h[j];  // write-buffer: no hazard
        }
        __syncthreads();
    }

    // final h lives in hl[TT & 1] == hl[0]
    float h[HDIM];
    #pragma unroll
    for (int k = 0; k < HDIM; ++k) h[k] = hl[0][nl * S + k];
    float xs[STATF];
    const float* xsrow = x_stat + (size_t)nclamp * STATF;
    #pragma unroll
    for (int k = 0; k < STATF; ++k) xs[k] = xsrow[k];

    float acc[16];
    #pragma unroll
    for (int jj = 0; jj < 16; ++jj) acc[jj] = 0.f;
    #pragma unroll
    for (int k = 0; k < HDIM; ++k) {
        #pragma unroll
        for (int jj = 0; jj < 16; ++jj)
            acc[jj] += h[k] * W1[k * HDIM + p * 16 + jj];
    }
    #pragma unroll
    for (int k = 0; k < STATF; ++k) {
        #pragma unroll
        for (int jj = 0; jj < 16; ++jj)
            acc[jj] += xs[k] * W1[(HDIM + k) * HDIM + p * 16 + jj];
    }
    if (valid) {
        #pragma unroll
        for (int jj = 0; jj < 16; ++jj)
            t1[(size_t)node * HDIM + p * 16 + jj] = acc[jj];
    }
}

// ---------------------------------------------------------------------------
// Edge scatter: one wave per edge, lane = feature. Coalesced 256B gather from
// src row, coalesced fp32 atomics into dst row.
// ---------------------------------------------------------------------------
__global__ __launch_bounds__(256) void scatter_kernel(
    const float* __restrict__ tsrc, const int* __restrict__ srcv,
    const int* __restrict__ dstv, const float* __restrict__ w,
    float* __restrict__ agg)
{
    const long long gid = (long long)blockIdx.x * 256 + threadIdx.x;
    const int e = (int)(gid >> 6);
    const int f = threadIdx.x & 63;
    if (e >= NEDGES) return;
    const int s = srcv[e];
    const int d = dstv[e];
    const float val = tsrc[(size_t)s * HDIM + f] * w[e];
    atomicAdd(&agg[(size_t)d * HDIM + f], val);
}

// ---------------------------------------------------------------------------
// h = relu(agg + bias); out = h @ W   (64x64). 4 threads/node, 16 outs each.
// ---------------------------------------------------------------------------
__global__ __launch_bounds__(256) void transform_kernel(
    const float* __restrict__ agg, const float* __restrict__ bias,
    const float* __restrict__ W, float* __restrict__ out)
{
    const int nl = threadIdx.x & 63;
    const int p = __builtin_amdgcn_readfirstlane((int)(threadIdx.x >> 6));
    const int node = blockIdx.x * 64 + nl;
    if (node >= NNODES) return;

    float in[HDIM];
    const float* arow = agg + (size_t)node * HDIM;
    #pragma unroll
    for (int c = 0; c < 16; ++c) {
        float4 v = *reinterpret_cast<const float4*>(arow + c * 4);
        in[c*4+0] = fmaxf(v.x + bias[c*4+0], 0.f);
        in[c*4+1] = fmaxf(v.y + bias[c*4+1], 0.f);
        in[c*4+2] = fmaxf(v.z + bias[c*4+2], 0.f);
        in[c*4+3] = fmaxf(v.w + bias[c*4+3], 0.f);
    }
    float acc[16];
    #pragma unroll
    for (int jj = 0; jj < 16; ++jj) acc[jj] = 0.f;
    #pragma unroll
    for (int k = 0; k < HDIM; ++k) {
        #pragma unroll
        for (int jj = 0; jj < 16; ++jj)
            acc[jj] += in[k] * W[k * HDIM + p * 16 + jj];
    }
    #pragma unroll
    for (int jj = 0; jj < 16; ++jj)
        out[(size_t)node * HDIM + p * 16 + jj] = acc[jj];
}

// ---------------------------------------------------------------------------
// Heads: h2 = relu(agg2 + b2); aqi = h2.Wa + ba; pm = h2.Wp + bp
// ---------------------------------------------------------------------------
__global__ __launch_bounds__(256) void head_kernel(
    const float* __restrict__ agg2, const float* __restrict__ b2,
    const float* __restrict__ Wa, const float* __restrict__ ba,
    const float* __restrict__ Wp, const float* __restrict__ bp,
    float* __restrict__ out)
{
    const int node = blockIdx.x * 256 + threadIdx.x;
    if (node >= NNODES) return;
    const float* arow = agg2 + (size_t)node * HDIM;
    float sa = 0.f, sp = 0.f;
    #pragma unroll
    for (int c = 0; c < 16; ++c) {
        float4 v = *reinterpret_cast<const float4*>(arow + c * 4);
        float h0 = fmaxf(v.x + b2[c*4+0], 0.f);
        float h1 = fmaxf(v.y + b2[c*4+1], 0.f);
        float h2 = fmaxf(v.z + b2[c*4+2], 0.f);
        float h3 = fmaxf(v.w + b2[c*4+3], 0.f);
        sa += h0 * Wa[c*4+0] + h1 * Wa[c*4+1] + h2 * Wa[c*4+2] + h3 * Wa[c*4+3];
        sp += h0 * Wp[c*4+0] + h1 * Wp[c*4+1] + h2 * Wp[c*4+2] + h3 * Wp[c*4+3];
    }
    out[node] = sa + ba[0];
    out[NNODES + node] = sp + bp[0];
}

extern "C" void kernel_launch(void* const* d_in, const int* in_sizes, int n_in,
                              void* d_out, int out_size, void* d_ws, size_t ws_size,
                              hipStream_t stream)
{
    const float* x_dyn  = (const float*)d_in[0];
    const float* x_stat = (const float*)d_in[1];
    const int*   eidx   = (const int*)  d_in[2];
    const float* ew     = (const float*)d_in[3];
    const float* Wih    = (const float*)d_in[4];
    const float* Whh    = (const float*)d_in[5];
    const float* bih    = (const float*)d_in[6];
    const float* bhh    = (const float*)d_in[7];
    const float* W1     = (const float*)d_in[8];
    const float* b1     = (const float*)d_in[9];
    const float* W2     = (const float*)d_in[10];
    const float* b2     = (const float*)d_in[11];
    const float* Wa     = (const float*)d_in[12];
    const float* ba     = (const float*)d_in[13];
    const float* Wp     = (const float*)d_in[14];
    const float* bp     = (const float*)d_in[15];

    const int* srcv = eidx;
    const int* dstv = eidx + NEDGES;

    float* ws   = (float*)d_ws;
    float* t1   = ws;
    float* agg1 = ws + (size_t)NNODES * HDIM;
    float* t2   = ws + 2 * (size_t)NNODES * HDIM;
    float* agg2 = ws + 3 * (size_t)NNODES * HDIM;

    hipMemsetAsync(agg1, 0, (size_t)NNODES * HDIM * sizeof(float), stream);
    hipMemsetAsync(agg2, 0, (size_t)NNODES * HDIM * sizeof(float), stream);

    dim3 blk(256);
    gru_w1_kernel<<<dim3((NNODES + 63) / 64), blk, 0, stream>>>(
        x_dyn, x_stat, Wih, Whh, bih, bhh, W1, t1);
    scatter_kernel<<<dim3(NEDGES / 4), blk, 0, stream>>>(t1, srcv, dstv, ew, agg1);
    transform_kernel<<<dim3((NNODES + 63) / 64), blk, 0, stream>>>(agg1, b1, W2, t2);
    scatter_kernel<<<dim3(NEDGES / 4), blk, 0, stream>>>(t2, srcv, dstv, ew, agg2);
    head_kernel<<<dim3((NNODES + 255) / 256), blk, 0, stream>>>(
        agg2, b2, Wa, ba, Wp, bp, (float*)d_out);
}